// Round 8
// baseline (346.048 us; speedup 1.0000x reference)
//
#include <hip/hip_runtime.h>
#include <math.h>

#define BB 64
#define SS 512
#define FF 128
#define UU 512
#define SIGDIM (FF + FF*FF)   // 16512
#define K3 16512              // sig GEMM K
#define KK 1152               // KAN GEMM K: 1024 spline + 128 base
#define NCH 32                // attn-reduction s-chunks

// k_prep block partitions
#define NB_WT2 4128           // (K3/64)*(UU/64)*2
#define NB_WT3 896            // 7*16*8 (with early-out)
#define NB_AD  1024           // 8 ttiles * 2 ftiles * 64 b
#define NB_WP  2304           // UU*KK/256
#define NB_PREP (NB_WT2 + NB_WT3 + NB_AD + NB_WP)

typedef __attribute__((ext_vector_type(8))) __bf16 bf16x8;
typedef __attribute__((ext_vector_type(4))) float f32x4;

union BFPACK { unsigned short s[8]; bf16x8 v; };

__device__ __forceinline__ unsigned short f2bf(float x) {
    unsigned int u = __float_as_uint(x);
    unsigned int r = u + 0x7FFFu + ((u >> 16) & 1u);   // RNE
    return (unsigned short)(r >> 16);
}

__device__ __forceinline__ float sigmoidf(float x) { return 1.0f / (1.0f + expf(-x)); }

// ---------------------------------------------------------------------------
// K1: merged prep. Linear block-id decode:
//  [0, NB_WT2):            w1/skip_w fp32 [K3][512] -> bf16 [512][K3]
//  [NB_WT2, +NB_WT3):      w2/w3/w4/gates transposes
//  [.., +NB_AD):           a/d signature operands -> bf16 aT/dT [b][f][512]
//  [.., +NB_WP):           KAN Wt + comb_b right half (h_prev)
// ---------------------------------------------------------------------------
__global__ __launch_bounds__(256) void k_prep(
        const float* __restrict__ inp, const float* __restrict__ tk,
        const float* __restrict__ splw, const float* __restrict__ basew,
        const float* __restrict__ hprev,
        const float* __restrict__ gw1, const float* __restrict__ gsw,
        const float* __restrict__ gw2, const float* __restrict__ gw3,
        const float* __restrict__ gw4, const float* __restrict__ wf,
        const float* __restrict__ wi, const float* __restrict__ wc,
        const float* __restrict__ wo,
        unsigned short* __restrict__ aT, unsigned short* __restrict__ dT,
        unsigned short* __restrict__ Wt, unsigned short* __restrict__ comb_b,
        unsigned short* __restrict__ W1t, unsigned short* __restrict__ Wst,
        unsigned short* __restrict__ W2t, unsigned short* __restrict__ W3t,
        unsigned short* __restrict__ W4t, unsigned short* __restrict__ Wgt) {
    __shared__ float sh[2 * 64 * 65 + 66];
    int id = blockIdx.x, tid = threadIdx.x;

    if (id < NB_WT2) {
        // big transpose: src [K3][512] fp32 -> dst [512][K3] bf16
        int mat = id / (NB_WT2 / 2);
        int rem = id % (NB_WT2 / 2);
        int kt = rem >> 3, ut = rem & 7;
        const float* src = mat ? gsw : gw1;
        unsigned short* dst = mat ? Wst : W1t;
        float* tile = sh;   // 64*65
        int k0 = kt * 64, u0 = ut * 64;
#pragma unroll
        for (int p = 0; p < 16; ++p) {
            int e = p * 256 + tid;
            int kk = e >> 6, uu = e & 63;
            tile[kk * 65 + uu] = src[(size_t)(k0 + kk) * UU + u0 + uu];
        }
        __syncthreads();
#pragma unroll
        for (int p = 0; p < 16; ++p) {
            int e = p * 256 + tid;
            int uu = e >> 6, kk = e & 63;
            dst[(size_t)(u0 + uu) * K3 + k0 + kk] = f2bf(tile[kk * 65 + uu]);
        }
        return;
    }
    if (id < NB_WT2 + NB_WT3) {
        int id2 = id - NB_WT2;
        int z = id2 >> 7;
        int rem = id2 & 127;
        int kt = rem >> 3, ut = rem & 7;
        int Kdim = (z < 3) ? 512 : 1024;
        if (kt * 64 >= Kdim) return;
        const float* src;
        unsigned short* dst;
        switch (z) {
            case 0: src = gw2; dst = W2t; break;
            case 1: src = gw3; dst = W3t; break;
            case 2: src = gw4; dst = W4t; break;
            case 3: src = wf; dst = Wgt; break;
            case 4: src = wi; dst = Wgt + (size_t)512 * 1024; break;
            case 5: src = wc; dst = Wgt + (size_t)1024 * 1024; break;
            default: src = wo; dst = Wgt + (size_t)1536 * 1024; break;
        }
        float* tile = sh;
        int k0 = kt * 64, u0 = ut * 64;
#pragma unroll
        for (int p = 0; p < 16; ++p) {
            int e = p * 256 + tid;
            int kk = e >> 6, uu = e & 63;
            tile[kk * 65 + uu] = src[(size_t)(k0 + kk) * UU + u0 + uu];
        }
        __syncthreads();
#pragma unroll
        for (int p = 0; p < 16; ++p) {
            int e = p * 256 + tid;
            int uu = e >> 6, kk = e & 63;
            dst[(size_t)(u0 + uu) * Kdim + k0 + kk] = f2bf(tile[kk * 65 + uu]);
        }
        return;
    }
    if (id < NB_WT2 + NB_WT3 + NB_AD) {
        int id3 = id - NB_WT2 - NB_WT3;
        int b = id3 & 63, ft = (id3 >> 6) & 1, tt = id3 >> 7;
        int tt0 = tt * 64, f0 = ft * 64;
        float* aS = sh;                 // 64*65
        float* dS = sh + 64 * 65;       // 64*65
        float* tkS = sh + 2 * 64 * 65;  // 65+1
        if (tid < 65) { int t = tt0 + tid; tkS[tid] = (t < SS) ? tk[t] : 0.f; }
        __syncthreads();
        const float* ib = inp + (size_t)b * SS * FF;
        float tk0 = tk[0];
        for (int e = tid; e < 64 * 64; e += 256) {
            int ttl = e >> 6, ff = e & 63;
            int t = tt0 + ttl;
            int f = f0 + ff;
            float av = 0.f, dv = 0.f;
            if (t < SS - 1) {
                float wa = tkS[ttl] * ib[(size_t)t * FF + f];
                float wn = tkS[ttl + 1] * ib[(size_t)(t + 1) * FF + f];
                float w0 = tk0 * ib[f];
                av = 0.5f * (wa + wn) - w0;
                dv = wn - wa;
            }
            aS[ttl * 65 + ff] = av; dS[ttl * 65 + ff] = dv;
        }
        __syncthreads();
        for (int e = tid; e < 64 * 64; e += 256) {
            int ff = e >> 6, ttl = e & 63;
            size_t o = ((size_t)b * FF + f0 + ff) * SS + tt0 + ttl;
            aT[o] = f2bf(aS[ttl * 65 + ff]);
            dT[o] = f2bf(dS[ttl * 65 + ff]);
        }
        return;
    }
    {
        int idx = (id - NB_WT2 - NB_WT3 - NB_AD) * 256 + tid;
        if (idx >= UU * KK) return;
        int u = idx / KK, c = idx % KK;
        float v = (c < 1024) ? splw[(size_t)u * 1024 + c] : basew[(size_t)(c - 1024) * UU + u];
        Wt[idx] = f2bf(v);
        if (idx < BB * UU) {
            int b = idx >> 9, uu = idx & 511;
            comb_b[(size_t)b * 1024 + 512 + uu] = f2bf(hprev[idx]);
        }
    }
}

// ---------------------------------------------------------------------------
// K2: fused signature: one block per b computes s2 = aT.dT^T (128x128, K=512)
// via MFMA direct loads and writes sigb bf16 directly; tid<128 writes s1 rows.
// ---------------------------------------------------------------------------
__global__ __launch_bounds__(256) void k_sig_fused(const unsigned short* __restrict__ aT,
                                                   const unsigned short* __restrict__ dT,
                                                   const float* __restrict__ inp,
                                                   const float* __restrict__ tk,
                                                   unsigned short* __restrict__ sigb) {
    int b = blockIdx.x;
    int tid = threadIdx.x, lane = tid & 63;
    int wv = __builtin_amdgcn_readfirstlane(tid >> 6);
    if (tid < 128) {
        const float* ib = inp + (size_t)b * SS * FF;
        float v = tk[SS - 1] * ib[(size_t)(SS - 1) * FF + tid] - tk[0] * ib[tid];
        sigb[(size_t)b * K3 + tid] = f2bf(v);
    }
    int wrow = (wv & 1) * 64, wcol = (wv >> 1) * 64;
    const unsigned short* pa = aT + ((size_t)b * FF + wrow + (lane & 15)) * SS + (lane >> 4) * 8;
    const unsigned short* pd = dT + ((size_t)b * FF + wcol + (lane & 15)) * SS + (lane >> 4) * 8;
    f32x4 acc[4][4];
#pragma unroll
    for (int i = 0; i < 4; ++i)
#pragma unroll
        for (int j = 0; j < 4; ++j) acc[i][j] = (f32x4)(0.f);
#pragma unroll 4
    for (int t = 0; t < 16; ++t) {
        bf16x8 af[4], df[4];
#pragma unroll
        for (int rt = 0; rt < 4; ++rt) af[rt] = *(const bf16x8*)(pa + (size_t)rt * 16 * SS + t * 32);
#pragma unroll
        for (int ct = 0; ct < 4; ++ct) df[ct] = *(const bf16x8*)(pd + (size_t)ct * 16 * SS + t * 32);
#pragma unroll
        for (int rt = 0; rt < 4; ++rt)
#pragma unroll
            for (int ct = 0; ct < 4; ++ct)
                acc[rt][ct] = __builtin_amdgcn_mfma_f32_16x16x32_bf16(af[rt], df[ct], acc[rt][ct], 0, 0, 0);
    }
    unsigned short* op = sigb + (size_t)b * K3 + 128;
    int quad = lane >> 4, col = lane & 15;
#pragma unroll
    for (int rt = 0; rt < 4; ++rt)
#pragma unroll
        for (int ct = 0; ct < 4; ++ct)
#pragma unroll
            for (int reg = 0; reg < 4; ++reg)
                op[(size_t)(wrow + rt * 16 + quad * 4 + reg) * FF + wcol + ct * 16 + col] =
                    f2bf(acc[rt][ct][reg]);
}

// ---------------------------------------------------------------------------
// K3: direct single-wave MFMA: {h1,skip} = sigb[64][16512] @ {W1t,Wst}^T
// ---------------------------------------------------------------------------
__global__ __launch_bounds__(64) void k_sig_direct(const unsigned short* __restrict__ sigb,
                                                   const unsigned short* __restrict__ W1t,
                                                   const unsigned short* __restrict__ Wst,
                                                   const float* __restrict__ b1,
                                                   unsigned short* __restrict__ h1b,
                                                   float* __restrict__ skippre) {
    int lane = threadIdx.x;
    int mt = blockIdx.x, nt = blockIdx.y, mat = blockIdx.z;
    const unsigned short* Bp = mat ? Wst : W1t;
    const unsigned short* pa = sigb + (size_t)(mt * 16 + (lane & 15)) * K3 + (lane >> 4) * 8;
    const unsigned short* pb = Bp + (size_t)(nt * 16 + (lane & 15)) * K3 + (lane >> 4) * 8;
    f32x4 acc0 = (f32x4)(0.f), acc1 = (f32x4)(0.f);
#pragma unroll 8
    for (int t = 0; t < K3 / 32; t += 2) {
        bf16x8 a0 = *(const bf16x8*)(pa + t * 32);
        bf16x8 b0 = *(const bf16x8*)(pb + t * 32);
        bf16x8 a1 = *(const bf16x8*)(pa + t * 32 + 32);
        bf16x8 b1v = *(const bf16x8*)(pb + t * 32 + 32);
        acc0 = __builtin_amdgcn_mfma_f32_16x16x32_bf16(a0, b0, acc0, 0, 0, 0);
        acc1 = __builtin_amdgcn_mfma_f32_16x16x32_bf16(a1, b1v, acc1, 0, 0, 0);
    }
    int col = lane & 15, quad = lane >> 4;
    int j = nt * 16 + col;
    if (mat == 0) {
        float bb = b1[j];
#pragma unroll
        for (int reg = 0; reg < 4; ++reg) {
            int row = mt * 16 + quad * 4 + reg;
            float v = acc0[reg] + acc1[reg] + bb;
            h1b[(size_t)row * UU + j] = f2bf(v > 0.f ? v : expf(v) - 1.0f);
        }
    } else {
#pragma unroll
        for (int reg = 0; reg < 4; ++reg) {
            int row = mt * 16 + quad * 4 + reg;
            skippre[(size_t)row * UU + j] = acc0[reg] + acc1[reg];
        }
    }
}

// ---------------------------------------------------------------------------
// K4: direct h2 = h1b @ W2t^T + b2 -> bf16
// ---------------------------------------------------------------------------
__global__ __launch_bounds__(64) void k_h2_direct(const unsigned short* __restrict__ h1b,
                                                  const unsigned short* __restrict__ W2t,
                                                  const float* __restrict__ b2,
                                                  unsigned short* __restrict__ h2b) {
    int lane = threadIdx.x;
    int mt = blockIdx.x, nt = blockIdx.y;
    const unsigned short* pa = h1b + (size_t)(mt * 16 + (lane & 15)) * 512 + (lane >> 4) * 8;
    const unsigned short* pb = W2t + (size_t)(nt * 16 + (lane & 15)) * 512 + (lane >> 4) * 8;
    f32x4 acc0 = (f32x4)(0.f), acc1 = (f32x4)(0.f);
#pragma unroll
    for (int t = 0; t < 16; t += 2) {
        bf16x8 a0 = *(const bf16x8*)(pa + t * 32);
        bf16x8 b0 = *(const bf16x8*)(pb + t * 32);
        bf16x8 a1 = *(const bf16x8*)(pa + t * 32 + 32);
        bf16x8 b1v = *(const bf16x8*)(pb + t * 32 + 32);
        acc0 = __builtin_amdgcn_mfma_f32_16x16x32_bf16(a0, b0, acc0, 0, 0, 0);
        acc1 = __builtin_amdgcn_mfma_f32_16x16x32_bf16(a1, b1v, acc1, 0, 0, 0);
    }
    int col = lane & 15, quad = lane >> 4;
    int j = nt * 16 + col;
    float bb = b2[j];
#pragma unroll
    for (int reg = 0; reg < 4; ++reg) {
        int row = mt * 16 + quad * 4 + reg;
        h2b[(size_t)row * UU + j] = f2bf(acc0[reg] + acc1[reg] + bb);
    }
}

// ---------------------------------------------------------------------------
// K5: direct GLU
// ---------------------------------------------------------------------------
__global__ __launch_bounds__(64) void k_glu_direct(const unsigned short* __restrict__ h2b,
                                                   const unsigned short* __restrict__ W3t,
                                                   const unsigned short* __restrict__ W4t,
                                                   const float* __restrict__ b3,
                                                   const float* __restrict__ b4,
                                                   const float* __restrict__ skippre,
                                                   const float* __restrict__ skb,
                                                   float* __restrict__ yv) {
    int lane = threadIdx.x;
    int mt = blockIdx.x, nt = blockIdx.y;
    const unsigned short* pa = h2b + (size_t)(mt * 16 + (lane & 15)) * 512 + (lane >> 4) * 8;
    const unsigned short* pb3 = W3t + (size_t)(nt * 16 + (lane & 15)) * 512 + (lane >> 4) * 8;
    const unsigned short* pb4 = W4t + (size_t)(nt * 16 + (lane & 15)) * 512 + (lane >> 4) * 8;
    f32x4 acc3 = (f32x4)(0.f), acc4 = (f32x4)(0.f);
#pragma unroll
    for (int t = 0; t < 16; ++t) {
        bf16x8 a = *(const bf16x8*)(pa + t * 32);
        bf16x8 b3f = *(const bf16x8*)(pb3 + t * 32);
        bf16x8 b4f = *(const bf16x8*)(pb4 + t * 32);
        acc3 = __builtin_amdgcn_mfma_f32_16x16x32_bf16(a, b3f, acc3, 0, 0, 0);
        acc4 = __builtin_amdgcn_mfma_f32_16x16x32_bf16(a, b4f, acc4, 0, 0, 0);
    }
    int col = lane & 15, quad = lane >> 4;
    int j = nt * 16 + col;
    float bb3 = b3[j], bb4 = b4[j], sb = skb[j];
#pragma unroll
    for (int reg = 0; reg < 4; ++reg) {
        int row = mt * 16 + quad * 4 + reg;
        float g = sigmoidf(acc3[reg] + bb3);
        yv[(size_t)row * UU + j] = skippre[(size_t)row * UU + j] + sb + g * (acc4[reg] + bb4);
    }
}

// ---------------------------------------------------------------------------
// K6: layernorm + softmax -> attn; also zeroes Ared for the next kernel.
// ---------------------------------------------------------------------------
__device__ __forceinline__ float block_sum(float v, float* red) {
    int tid = threadIdx.x;
#pragma unroll
    for (int off = 32; off > 0; off >>= 1) v += __shfl_down(v, off);
    __syncthreads();
    if ((tid & 63) == 0) red[tid >> 6] = v;
    __syncthreads();
    float r = red[0];
#pragma unroll
    for (int i = 1; i < 8; ++i) r += red[i];
    return r;
}
__device__ __forceinline__ float block_max(float v, float* red) {
    int tid = threadIdx.x;
#pragma unroll
    for (int off = 32; off > 0; off >>= 1) v = fmaxf(v, __shfl_down(v, off));
    __syncthreads();
    if ((tid & 63) == 0) red[tid >> 6] = v;
    __syncthreads();
    float r = red[0];
#pragma unroll
    for (int i = 1; i < 8; ++i) r = fmaxf(r, red[i]);
    return r;
}

__global__ void k_lnsm(const float* __restrict__ yv, const float* __restrict__ gamma,
                       const float* __restrict__ beta, float* __restrict__ attn,
                       float* __restrict__ Ared) {
    int b = blockIdx.x, u = threadIdx.x;
    int gid = b * UU + u;
    for (int i = gid; i < BB * KK; i += BB * UU) Ared[i] = 0.f;
    __shared__ float red[8];
    float v = yv[(size_t)b * UU + u];
    float mu = block_sum(v, red) * (1.0f / UU);
    float d = v - mu;
    float var = block_sum(d * d, red) * (1.0f / UU);
    float z = d * rsqrtf(var + 1e-3f) * gamma[u] + beta[u];
    float m = block_max(z, red);
    float e = expf(z - m);
    float Z = block_sum(e, red);
    attn[(size_t)b * UU + u] = e / Z;
}

// ---------------------------------------------------------------------------
// K7: attn-weighted KAN-feature reduction.  Closed-form cubic B-spline,
// scatter into per-thread LDS bins (stride 9 -> conflict-free), epilogue
// atomicAdd into fp32 Ared (pre-zeroed by k_lnsm).
// ---------------------------------------------------------------------------
__global__ __launch_bounds__(128) void k_attn_red(const float* __restrict__ inp,
                                                  const float* __restrict__ tk,
                                                  const float* __restrict__ attn,
                                                  float* __restrict__ Ared) {
    int b = blockIdx.x, ch = blockIdx.y;
    int tid = threadIdx.x;
    __shared__ float attnS[16], tkS[16];
    __shared__ float lacc[128 * 9];
    float* myacc = lacc + tid * 9;
#pragma unroll
    for (int j = 0; j < 8; ++j) myacc[j] = 0.f;
    if (tid < 16) { attnS[tid] = attn[(size_t)b * UU + ch * 16 + tid]; tkS[tid] = tk[ch * 16 + tid]; }
    __syncthreads();
    const float* ib = inp + ((size_t)b * SS + ch * 16) * FF + tid;
    float accS = 0.f;
#pragma unroll
    for (int s = 0; s < 16; ++s) {
        float w = tkS[s] * ib[(size_t)s * FF];
        float a = attnS[s];
        float t = (w + 2.2f) * 2.5f;
        float cf = floorf(fminf(fmaxf(t, -2.f), 13.f));
        int c = (int)cf;
        float u = t - cf;
        float u2 = u * u, u3 = u2 * u;
        float p[4];
        p[0] = u3 * (1.f / 6.f);
        p[1] = (-3.f * u3 + 3.f * u2 + 3.f * u + 1.f) * (1.f / 6.f);
        p[2] = (3.f * u3 - 6.f * u2 + 4.f) * (1.f / 6.f);
        float onemu = 1.f - u;
        p[3] = onemu * onemu * onemu * (1.f / 6.f);
#pragma unroll
        for (int j = 0; j < 4; ++j) {
            int k2 = c - j;
            bool ok = (k2 >= 0) && (k2 < 8);
            int ka = ok ? k2 : 0;
            float val = ok ? a * p[j] : 0.f;
            myacc[ka] += val;
        }
        accS += a * (w * sigmoidf(w));
    }
    float* op = Ared + (size_t)b * KK;
#pragma unroll
    for (int j = 0; j < 8; ++j) atomicAdd(op + tid * 8 + j, myacc[j]);
    atomicAdd(op + 1024 + tid, accS);
}

// ---------------------------------------------------------------------------
// K8: direct current = (Ared/S) @ Wt^T -> bf16 into comb_b left half.
// A operand converted fp32->bf16 inline.
// ---------------------------------------------------------------------------
__global__ __launch_bounds__(64) void k_cur_direct(const float* __restrict__ Ared,
                                                   const unsigned short* __restrict__ Wt,
                                                   unsigned short* __restrict__ comb_b) {
    int lane = threadIdx.x;
    int mt = blockIdx.x, nt = blockIdx.y;
    const float* pa = Ared + (size_t)(mt * 16 + (lane & 15)) * KK + (lane >> 4) * 8;
    const unsigned short* pb = Wt + (size_t)(nt * 16 + (lane & 15)) * KK + (lane >> 4) * 8;
    const float sc = 1.0f / SS;
    f32x4 acc0 = (f32x4)(0.f);
#pragma unroll 6
    for (int t = 0; t < KK / 32; ++t) {
        float4 f0 = *(const float4*)(pa + t * 32);
        float4 f1 = *(const float4*)(pa + t * 32 + 4);
        BFPACK ap;
        ap.s[0] = f2bf(f0.x * sc); ap.s[1] = f2bf(f0.y * sc);
        ap.s[2] = f2bf(f0.z * sc); ap.s[3] = f2bf(f0.w * sc);
        ap.s[4] = f2bf(f1.x * sc); ap.s[5] = f2bf(f1.y * sc);
        ap.s[6] = f2bf(f1.z * sc); ap.s[7] = f2bf(f1.w * sc);
        bf16x8 bfr = *(const bf16x8*)(pb + t * 32);
        acc0 = __builtin_amdgcn_mfma_f32_16x16x32_bf16(ap.v, bfr, acc0, 0, 0, 0);
    }
    int col = lane & 15, quad = lane >> 4;
    int j = nt * 16 + col;
#pragma unroll
    for (int reg = 0; reg < 4; ++reg) {
        int row = mt * 16 + quad * 4 + reg;
        comb_b[(size_t)row * 1024 + j] = f2bf(acc0[reg]);
    }
}

// ---------------------------------------------------------------------------
// K9: fused gates + LSTM cell.  Each block computes one (16b x 16u) tile for
// ALL four gates (4 B-streams over Wgt) and applies the cell update.
// grid (4 mt, 32 ut) x 64.
// ---------------------------------------------------------------------------
__global__ __launch_bounds__(64) void k_lstm_direct(const unsigned short* __restrict__ comb_b,
                                                    const unsigned short* __restrict__ Wgt,
                                                    const float* __restrict__ bf_,
                                                    const float* __restrict__ bi_,
                                                    const float* __restrict__ bc_,
                                                    const float* __restrict__ bo_,
                                                    const float* __restrict__ c_prev,
                                                    float* __restrict__ out) {
    int lane = threadIdx.x;
    int mt = blockIdx.x, ut = blockIdx.y;
    const unsigned short* pa = comb_b + (size_t)(mt * 16 + (lane & 15)) * 1024 + (lane >> 4) * 8;
    size_t brow = (size_t)(ut * 16 + (lane & 15)) * 1024 + (lane >> 4) * 8;
    const unsigned short* pbF = Wgt + brow;
    const unsigned short* pbI = Wgt + (size_t)512 * 1024 + brow;
    const unsigned short* pbC = Wgt + (size_t)1024 * 1024 + brow;
    const unsigned short* pbO = Wgt + (size_t)1536 * 1024 + brow;
    f32x4 aF = (f32x4)(0.f), aI = (f32x4)(0.f), aC = (f32x4)(0.f), aO = (f32x4)(0.f);
#pragma unroll 8
    for (int t = 0; t < 32; ++t) {
        bf16x8 a = *(const bf16x8*)(pa + t * 32);
        aF = __builtin_amdgcn_mfma_f32_16x16x32_bf16(a, *(const bf16x8*)(pbF + t * 32), aF, 0, 0, 0);
        aI = __builtin_amdgcn_mfma_f32_16x16x32_bf16(a, *(const bf16x8*)(pbI + t * 32), aI, 0, 0, 0);
        aC = __builtin_amdgcn_mfma_f32_16x16x32_bf16(a, *(const bf16x8*)(pbC + t * 32), aC, 0, 0, 0);
        aO = __builtin_amdgcn_mfma_f32_16x16x32_bf16(a, *(const bf16x8*)(pbO + t * 32), aO, 0, 0, 0);
    }
    int col = lane & 15, quad = lane >> 4;
    int j = ut * 16 + col;
    float bF = bf_[j], bI = bi_[j], bC = bc_[j], bO = bo_[j];
#pragma unroll
    for (int reg = 0; reg < 4; ++reg) {
        int row = mt * 16 + quad * 4 + reg;
        size_t o = (size_t)row * UU + j;
        float f = sigmoidf(aF[reg] + bF);
        float ii = sigmoidf(aI[reg] + bI);
        float cd = tanhf(aC[reg] + bC);
        float oo = sigmoidf(aO[reg] + bO);
        float cn = f * c_prev[o] + ii * cd;
        out[o] = oo * tanhf(cn);
        out[(size_t)BB * UU + o] = cn;
    }
}

// ---------------------------------------------------------------------------
extern "C" void kernel_launch(void* const* d_in, const int* in_sizes, int n_in,
                              void* d_out, int out_size, void* d_ws, size_t ws_size,
                              hipStream_t stream) {
    const float* inp   = (const float*)d_in[0];
    const float* hprev = (const float*)d_in[1];
    const float* cprev = (const float*)d_in[2];
    const float* tk    = (const float*)d_in[3];
    const float* basew = (const float*)d_in[4];
    const float* splw  = (const float*)d_in[5];
    const float* gw1   = (const float*)d_in[6];
    const float* gb1   = (const float*)d_in[7];
    const float* gw2   = (const float*)d_in[8];
    const float* gb2   = (const float*)d_in[9];
    const float* gw3   = (const float*)d_in[10];
    const float* gb3   = (const float*)d_in[11];
    const float* gw4   = (const float*)d_in[12];
    const float* gb4   = (const float*)d_in[13];
    const float* gsw   = (const float*)d_in[14];
    const float* gsb   = (const float*)d_in[15];
    const float* lng   = (const float*)d_in[16];
    const float* lnb   = (const float*)d_in[17];
    const float* wf    = (const float*)d_in[18];
    const float* bf_   = (const float*)d_in[19];
    const float* wi    = (const float*)d_in[20];
    const float* bi_   = (const float*)d_in[21];
    const float* wc    = (const float*)d_in[22];
    const float* bc_   = (const float*)d_in[23];
    const float* wo    = (const float*)d_in[24];
    const float* bo_   = (const float*)d_in[25];
    float* out = (float*)d_out;

    float* ws = (float*)d_ws;
    size_t o = 0;
    unsigned short* W1t = (unsigned short*)(ws + o); o += (size_t)UU * K3 / 2;      // 16.9 MB
    unsigned short* Wst = (unsigned short*)(ws + o); o += (size_t)UU * K3 / 2;      // 16.9 MB
    unsigned short* Wt  = (unsigned short*)(ws + o); o += (size_t)UU * KK / 2;
    unsigned short* aT = (unsigned short*)(ws + o); o += (size_t)BB * FF * SS / 2;  // 8.4 MB
    unsigned short* dT = (unsigned short*)(ws + o); o += (size_t)BB * FF * SS / 2;  // 8.4 MB
    unsigned short* sigb = (unsigned short*)(ws + o); o += (size_t)BB * K3 / 2;
    float* skippre  = ws + o; o += (size_t)BB * UU;
    unsigned short* h1b = (unsigned short*)(ws + o); o += (size_t)BB * UU / 2;
    unsigned short* h2b = (unsigned short*)(ws + o); o += (size_t)BB * UU / 2;
    float* yv       = ws + o; o += (size_t)BB * UU;
    float* attn     = ws + o; o += (size_t)BB * UU;
    float* Ared     = ws + o; o += (size_t)BB * KK;                                 // 0.3 MB fp32
    unsigned short* W2t = (unsigned short*)(ws + o); o += (size_t)512 * 512 / 2;
    unsigned short* W3t = (unsigned short*)(ws + o); o += (size_t)512 * 512 / 2;
    unsigned short* W4t = (unsigned short*)(ws + o); o += (size_t)512 * 512 / 2;
    unsigned short* Wgt = (unsigned short*)(ws + o); o += (size_t)2048 * 1024 / 2;
    unsigned short* comb_b = (unsigned short*)(ws + o); o += (size_t)BB * 1024 / 2;
    (void)ws_size; (void)in_sizes; (void)n_in; (void)out_size;

    k_prep<<<NB_PREP, 256, 0, stream>>>(inp, tk, splw, basew, hprev, gw1, gsw, gw2, gw3, gw4,
                                        wf, wi, wc, wo, aT, dT, Wt, comb_b,
                                        W1t, Wst, W2t, W3t, W4t, Wgt);
    k_sig_fused<<<BB, 256, 0, stream>>>(aT, dT, inp, tk, sigb);
    k_sig_direct<<<dim3(4, 32, 2), 64, 0, stream>>>(sigb, W1t, Wst, gb1, h1b, skippre);
    k_h2_direct<<<dim3(4, 32), 64, 0, stream>>>(h1b, W2t, gb2, h2b);
    k_glu_direct<<<dim3(4, 32), 64, 0, stream>>>(h2b, W3t, W4t, gb3, gb4, skippre, gsb, yv);
    k_lnsm<<<BB, UU, 0, stream>>>(yv, lng, lnb, attn, Ared);
    k_attn_red<<<dim3(BB, NCH), 128, 0, stream>>>(inp, tk, attn, Ared);
    k_cur_direct<<<dim3(4, 32), 64, 0, stream>>>(Ared, Wt, comb_b);
    k_lstm_direct<<<dim3(4, 32), 64, 0, stream>>>(comb_b, Wgt, bf_, bi_, bc_, bo_, cprev, out);
}

// Round 9
// 345.021 us; speedup vs baseline: 1.0030x; 1.0030x over previous
//
#include <hip/hip_runtime.h>
#include <math.h>

#define BB 64
#define SS 512
#define FF 128
#define UU 512
#define SIGDIM (FF + FF*FF)   // 16512
#define K3 16512              // sig GEMM K
#define KK 1152               // KAN GEMM K: 1024 spline + 128 base
#define NCH 32                // attn-reduction s-chunks

// k_prep block partitions
#define NB_WT2 4128           // (K3/64)*(UU/64)*2
#define NB_WT3 896            // 7*16*8 (with early-out)
#define NB_AD  1024           // 8 ttiles * 2 ftiles * 64 b
#define NB_WP  2304           // UU*KK/256
#define NB_PREP (NB_WT2 + NB_WT3 + NB_AD + NB_WP)

typedef __attribute__((ext_vector_type(8))) __bf16 bf16x8;
typedef __attribute__((ext_vector_type(4))) float f32x4;

__device__ __forceinline__ unsigned short f2bf(float x) {
    unsigned int u = __float_as_uint(x);
    unsigned int r = u + 0x7FFFu + ((u >> 16) & 1u);   // RNE
    return (unsigned short)(r >> 16);
}

__device__ __forceinline__ float sigmoidf(float x) { return 1.0f / (1.0f + expf(-x)); }

// ---------------------------------------------------------------------------
// K1: merged prep (unchanged from R7)
// ---------------------------------------------------------------------------
__global__ __launch_bounds__(256) void k_prep(
        const float* __restrict__ inp, const float* __restrict__ tk,
        const float* __restrict__ splw, const float* __restrict__ basew,
        const float* __restrict__ hprev,
        const float* __restrict__ gw1, const float* __restrict__ gsw,
        const float* __restrict__ gw2, const float* __restrict__ gw3,
        const float* __restrict__ gw4, const float* __restrict__ wf,
        const float* __restrict__ wi, const float* __restrict__ wc,
        const float* __restrict__ wo,
        unsigned short* __restrict__ aT, unsigned short* __restrict__ dT,
        unsigned short* __restrict__ Wt, unsigned short* __restrict__ comb_b,
        unsigned short* __restrict__ W1t, unsigned short* __restrict__ Wst,
        unsigned short* __restrict__ W2t, unsigned short* __restrict__ W3t,
        unsigned short* __restrict__ W4t, unsigned short* __restrict__ Wgt) {
    __shared__ float sh[2 * 64 * 65 + 66];
    int id = blockIdx.x, tid = threadIdx.x;

    if (id < NB_WT2) {
        int mat = id / (NB_WT2 / 2);
        int rem = id % (NB_WT2 / 2);
        int kt = rem >> 3, ut = rem & 7;
        const float* src = mat ? gsw : gw1;
        unsigned short* dst = mat ? Wst : W1t;
        float* tile = sh;
        int k0 = kt * 64, u0 = ut * 64;
#pragma unroll
        for (int p = 0; p < 16; ++p) {
            int e = p * 256 + tid;
            int kk = e >> 6, uu = e & 63;
            tile[kk * 65 + uu] = src[(size_t)(k0 + kk) * UU + u0 + uu];
        }
        __syncthreads();
#pragma unroll
        for (int p = 0; p < 16; ++p) {
            int e = p * 256 + tid;
            int uu = e >> 6, kk = e & 63;
            dst[(size_t)(u0 + uu) * K3 + k0 + kk] = f2bf(tile[kk * 65 + uu]);
        }
        return;
    }
    if (id < NB_WT2 + NB_WT3) {
        int id2 = id - NB_WT2;
        int z = id2 >> 7;
        int rem = id2 & 127;
        int kt = rem >> 3, ut = rem & 7;
        int Kdim = (z < 3) ? 512 : 1024;
        if (kt * 64 >= Kdim) return;
        const float* src;
        unsigned short* dst;
        switch (z) {
            case 0: src = gw2; dst = W2t; break;
            case 1: src = gw3; dst = W3t; break;
            case 2: src = gw4; dst = W4t; break;
            case 3: src = wf; dst = Wgt; break;
            case 4: src = wi; dst = Wgt + (size_t)512 * 1024; break;
            case 5: src = wc; dst = Wgt + (size_t)1024 * 1024; break;
            default: src = wo; dst = Wgt + (size_t)1536 * 1024; break;
        }
        float* tile = sh;
        int k0 = kt * 64, u0 = ut * 64;
#pragma unroll
        for (int p = 0; p < 16; ++p) {
            int e = p * 256 + tid;
            int kk = e >> 6, uu = e & 63;
            tile[kk * 65 + uu] = src[(size_t)(k0 + kk) * UU + u0 + uu];
        }
        __syncthreads();
#pragma unroll
        for (int p = 0; p < 16; ++p) {
            int e = p * 256 + tid;
            int uu = e >> 6, kk = e & 63;
            dst[(size_t)(u0 + uu) * Kdim + k0 + kk] = f2bf(tile[kk * 65 + uu]);
        }
        return;
    }
    if (id < NB_WT2 + NB_WT3 + NB_AD) {
        int id3 = id - NB_WT2 - NB_WT3;
        int b = id3 & 63, ft = (id3 >> 6) & 1, tt = id3 >> 7;
        int tt0 = tt * 64, f0 = ft * 64;
        float* aS = sh;
        float* dS = sh + 64 * 65;
        float* tkS = sh + 2 * 64 * 65;
        if (tid < 65) { int t = tt0 + tid; tkS[tid] = (t < SS) ? tk[t] : 0.f; }
        __syncthreads();
        const float* ib = inp + (size_t)b * SS * FF;
        float tk0 = tk[0];
        for (int e = tid; e < 64 * 64; e += 256) {
            int ttl = e >> 6, ff = e & 63;
            int t = tt0 + ttl;
            int f = f0 + ff;
            float av = 0.f, dv = 0.f;
            if (t < SS - 1) {
                float wa = tkS[ttl] * ib[(size_t)t * FF + f];
                float wn = tkS[ttl + 1] * ib[(size_t)(t + 1) * FF + f];
                float w0 = tk0 * ib[f];
                av = 0.5f * (wa + wn) - w0;
                dv = wn - wa;
            }
            aS[ttl * 65 + ff] = av; dS[ttl * 65 + ff] = dv;
        }
        __syncthreads();
        for (int e = tid; e < 64 * 64; e += 256) {
            int ff = e >> 6, ttl = e & 63;
            size_t o = ((size_t)b * FF + f0 + ff) * SS + tt0 + ttl;
            aT[o] = f2bf(aS[ttl * 65 + ff]);
            dT[o] = f2bf(dS[ttl * 65 + ff]);
        }
        return;
    }
    {
        int idx = (id - NB_WT2 - NB_WT3 - NB_AD) * 256 + tid;
        if (idx >= UU * KK) return;
        int u = idx / KK, c = idx % KK;
        float v = (c < 1024) ? splw[(size_t)u * 1024 + c] : basew[(size_t)(c - 1024) * UU + u];
        Wt[idx] = f2bf(v);
        if (idx < BB * UU) {
            int b = idx >> 9, uu = idx & 511;
            comb_b[(size_t)b * 1024 + 512 + uu] = f2bf(hprev[idx]);
        }
    }
}

// ---------------------------------------------------------------------------
// K2: fused signature (unchanged from R7)
// ---------------------------------------------------------------------------
__global__ __launch_bounds__(256) void k_sig_fused(const unsigned short* __restrict__ aT,
                                                   const unsigned short* __restrict__ dT,
                                                   const float* __restrict__ inp,
                                                   const float* __restrict__ tk,
                                                   unsigned short* __restrict__ sigb) {
    int b = blockIdx.x;
    int tid = threadIdx.x, lane = tid & 63;
    int wv = __builtin_amdgcn_readfirstlane(tid >> 6);
    if (tid < 128) {
        const float* ib = inp + (size_t)b * SS * FF;
        float v = tk[SS - 1] * ib[(size_t)(SS - 1) * FF + tid] - tk[0] * ib[tid];
        sigb[(size_t)b * K3 + tid] = f2bf(v);
    }
    int wrow = (wv & 1) * 64, wcol = (wv >> 1) * 64;
    const unsigned short* pa = aT + ((size_t)b * FF + wrow + (lane & 15)) * SS + (lane >> 4) * 8;
    const unsigned short* pd = dT + ((size_t)b * FF + wcol + (lane & 15)) * SS + (lane >> 4) * 8;
    f32x4 acc[4][4];
#pragma unroll
    for (int i = 0; i < 4; ++i)
#pragma unroll
        for (int j = 0; j < 4; ++j) acc[i][j] = (f32x4)(0.f);
#pragma unroll 4
    for (int t = 0; t < 16; ++t) {
        bf16x8 af[4], df[4];
#pragma unroll
        for (int rt = 0; rt < 4; ++rt) af[rt] = *(const bf16x8*)(pa + (size_t)rt * 16 * SS + t * 32);
#pragma unroll
        for (int ct = 0; ct < 4; ++ct) df[ct] = *(const bf16x8*)(pd + (size_t)ct * 16 * SS + t * 32);
#pragma unroll
        for (int rt = 0; rt < 4; ++rt)
#pragma unroll
            for (int ct = 0; ct < 4; ++ct)
                acc[rt][ct] = __builtin_amdgcn_mfma_f32_16x16x32_bf16(af[rt], df[ct], acc[rt][ct], 0, 0, 0);
    }
    unsigned short* op = sigb + (size_t)b * K3 + 128;
    int quad = lane >> 4, col = lane & 15;
#pragma unroll
    for (int rt = 0; rt < 4; ++rt)
#pragma unroll
        for (int ct = 0; ct < 4; ++ct)
#pragma unroll
            for (int reg = 0; reg < 4; ++reg)
                op[(size_t)(wrow + rt * 16 + quad * 4 + reg) * FF + wcol + ct * 16 + col] =
                    f2bf(acc[rt][ct][reg]);
}

// ---------------------------------------------------------------------------
// K3: split-K direct MFMA: {h1,skip} = sigb[64][16512] @ {W1t,Wst}^T.
// 256 thr = 4 waves, each takes K/4 = 4128 (129 chunks of 32); LDS reduce.
// grid (4 mt, 32 nt, 2 mat).
// ---------------------------------------------------------------------------
__global__ __launch_bounds__(256) void k_sig_direct(const unsigned short* __restrict__ sigb,
                                                    const unsigned short* __restrict__ W1t,
                                                    const unsigned short* __restrict__ Wst,
                                                    const float* __restrict__ b1,
                                                    unsigned short* __restrict__ h1b,
                                                    float* __restrict__ skippre) {
    __shared__ float red[4][64][4];
    int tid = threadIdx.x, lane = tid & 63;
    int wv = tid >> 6;
    int mt = blockIdx.x, nt = blockIdx.y, mat = blockIdx.z;
    const unsigned short* Bp = mat ? Wst : W1t;
    size_t kofs = (size_t)wv * 4128 + (lane >> 4) * 8;
    const unsigned short* pa = sigb + (size_t)(mt * 16 + (lane & 15)) * K3 + kofs;
    const unsigned short* pb = Bp + (size_t)(nt * 16 + (lane & 15)) * K3 + kofs;
    f32x4 acc0 = (f32x4)(0.f), acc1 = (f32x4)(0.f);
#pragma unroll 8
    for (int t = 0; t < 128; t += 2) {
        bf16x8 a0 = *(const bf16x8*)(pa + t * 32);
        bf16x8 b0 = *(const bf16x8*)(pb + t * 32);
        bf16x8 a1 = *(const bf16x8*)(pa + t * 32 + 32);
        bf16x8 b1v = *(const bf16x8*)(pb + t * 32 + 32);
        acc0 = __builtin_amdgcn_mfma_f32_16x16x32_bf16(a0, b0, acc0, 0, 0, 0);
        acc1 = __builtin_amdgcn_mfma_f32_16x16x32_bf16(a1, b1v, acc1, 0, 0, 0);
    }
    {   // 129th chunk
        bf16x8 a0 = *(const bf16x8*)(pa + 128 * 32);
        bf16x8 b0 = *(const bf16x8*)(pb + 128 * 32);
        acc0 = __builtin_amdgcn_mfma_f32_16x16x32_bf16(a0, b0, acc0, 0, 0, 0);
    }
#pragma unroll
    for (int r = 0; r < 4; ++r) red[wv][lane][r] = acc0[r] + acc1[r];
    __syncthreads();
    if (wv == 0) {
        int col = lane & 15, quad = lane >> 4;
        int j = nt * 16 + col;
        float v4[4];
#pragma unroll
        for (int r = 0; r < 4; ++r)
            v4[r] = red[0][lane][r] + red[1][lane][r] + red[2][lane][r] + red[3][lane][r];
        if (mat == 0) {
            float bb = b1[j];
#pragma unroll
            for (int reg = 0; reg < 4; ++reg) {
                int row = mt * 16 + quad * 4 + reg;
                float v = v4[reg] + bb;
                h1b[(size_t)row * UU + j] = f2bf(v > 0.f ? v : expf(v) - 1.0f);
            }
        } else {
#pragma unroll
            for (int reg = 0; reg < 4; ++reg) {
                int row = mt * 16 + quad * 4 + reg;
                skippre[(size_t)row * UU + j] = v4[reg];
            }
        }
    }
}

// ---------------------------------------------------------------------------
// K4: direct h2 = h1b @ W2t^T + b2 -> bf16
// ---------------------------------------------------------------------------
__global__ __launch_bounds__(64) void k_h2_direct(const unsigned short* __restrict__ h1b,
                                                  const unsigned short* __restrict__ W2t,
                                                  const float* __restrict__ b2,
                                                  unsigned short* __restrict__ h2b) {
    int lane = threadIdx.x;
    int mt = blockIdx.x, nt = blockIdx.y;
    const unsigned short* pa = h1b + (size_t)(mt * 16 + (lane & 15)) * 512 + (lane >> 4) * 8;
    const unsigned short* pb = W2t + (size_t)(nt * 16 + (lane & 15)) * 512 + (lane >> 4) * 8;
    f32x4 acc0 = (f32x4)(0.f), acc1 = (f32x4)(0.f);
#pragma unroll
    for (int t = 0; t < 16; t += 2) {
        bf16x8 a0 = *(const bf16x8*)(pa + t * 32);
        bf16x8 b0 = *(const bf16x8*)(pb + t * 32);
        bf16x8 a1 = *(const bf16x8*)(pa + t * 32 + 32);
        bf16x8 b1v = *(const bf16x8*)(pb + t * 32 + 32);
        acc0 = __builtin_amdgcn_mfma_f32_16x16x32_bf16(a0, b0, acc0, 0, 0, 0);
        acc1 = __builtin_amdgcn_mfma_f32_16x16x32_bf16(a1, b1v, acc1, 0, 0, 0);
    }
    int col = lane & 15, quad = lane >> 4;
    int j = nt * 16 + col;
    float bb = b2[j];
#pragma unroll
    for (int reg = 0; reg < 4; ++reg) {
        int row = mt * 16 + quad * 4 + reg;
        h2b[(size_t)row * UU + j] = f2bf(acc0[reg] + acc1[reg] + bb);
    }
}

// ---------------------------------------------------------------------------
// K5: direct GLU
// ---------------------------------------------------------------------------
__global__ __launch_bounds__(64) void k_glu_direct(const unsigned short* __restrict__ h2b,
                                                   const unsigned short* __restrict__ W3t,
                                                   const unsigned short* __restrict__ W4t,
                                                   const float* __restrict__ b3,
                                                   const float* __restrict__ b4,
                                                   const float* __restrict__ skippre,
                                                   const float* __restrict__ skb,
                                                   float* __restrict__ yv) {
    int lane = threadIdx.x;
    int mt = blockIdx.x, nt = blockIdx.y;
    const unsigned short* pa = h2b + (size_t)(mt * 16 + (lane & 15)) * 512 + (lane >> 4) * 8;
    const unsigned short* pb3 = W3t + (size_t)(nt * 16 + (lane & 15)) * 512 + (lane >> 4) * 8;
    const unsigned short* pb4 = W4t + (size_t)(nt * 16 + (lane & 15)) * 512 + (lane >> 4) * 8;
    f32x4 acc3 = (f32x4)(0.f), acc4 = (f32x4)(0.f);
#pragma unroll
    for (int t = 0; t < 16; ++t) {
        bf16x8 a = *(const bf16x8*)(pa + t * 32);
        bf16x8 b3f = *(const bf16x8*)(pb3 + t * 32);
        bf16x8 b4f = *(const bf16x8*)(pb4 + t * 32);
        acc3 = __builtin_amdgcn_mfma_f32_16x16x32_bf16(a, b3f, acc3, 0, 0, 0);
        acc4 = __builtin_amdgcn_mfma_f32_16x16x32_bf16(a, b4f, acc4, 0, 0, 0);
    }
    int col = lane & 15, quad = lane >> 4;
    int j = nt * 16 + col;
    float bb3 = b3[j], bb4 = b4[j], sb = skb[j];
#pragma unroll
    for (int reg = 0; reg < 4; ++reg) {
        int row = mt * 16 + quad * 4 + reg;
        float g = sigmoidf(acc3[reg] + bb3);
        yv[(size_t)row * UU + j] = skippre[(size_t)row * UU + j] + sb + g * (acc4[reg] + bb4);
    }
}

// ---------------------------------------------------------------------------
// K6: layernorm + softmax -> attn
// ---------------------------------------------------------------------------
__device__ __forceinline__ float block_sum(float v, float* red) {
    int tid = threadIdx.x;
#pragma unroll
    for (int off = 32; off > 0; off >>= 1) v += __shfl_down(v, off);
    __syncthreads();
    if ((tid & 63) == 0) red[tid >> 6] = v;
    __syncthreads();
    float r = red[0];
#pragma unroll
    for (int i = 1; i < 8; ++i) r += red[i];
    return r;
}
__device__ __forceinline__ float block_max(float v, float* red) {
    int tid = threadIdx.x;
#pragma unroll
    for (int off = 32; off > 0; off >>= 1) v = fmaxf(v, __shfl_down(v, off));
    __syncthreads();
    if ((tid & 63) == 0) red[tid >> 6] = v;
    __syncthreads();
    float r = red[0];
#pragma unroll
    for (int i = 1; i < 8; ++i) r = fmaxf(r, red[i]);
    return r;
}

__global__ void k_lnsm(const float* __restrict__ yv, const float* __restrict__ gamma,
                       const float* __restrict__ beta, float* __restrict__ attn) {
    int b = blockIdx.x, u = threadIdx.x;
    __shared__ float red[8];
    float v = yv[(size_t)b * UU + u];
    float mu = block_sum(v, red) * (1.0f / UU);
    float d = v - mu;
    float var = block_sum(d * d, red) * (1.0f / UU);
    float z = d * rsqrtf(var + 1e-3f) * gamma[u] + beta[u];
    float m = block_max(z, red);
    float e = expf(z - m);
    float Z = block_sum(e, red);
    attn[(size_t)b * UU + u] = e / Z;
}

// ---------------------------------------------------------------------------
// K7: attn-weighted KAN-feature reduction.  Closed-form cubic B-spline;
// per-thread LDS bins updated via shared-memory atomicAdd (ds_add_f32,
// fire-and-forget: no dependent RMW chain, no register selects).
// Private per-(b,ch) global output (no global atomics).
// ---------------------------------------------------------------------------
__global__ __launch_bounds__(128) void k_attn_red(const float* __restrict__ inp,
                                                  const float* __restrict__ tk,
                                                  const float* __restrict__ attn,
                                                  float* __restrict__ Apart) {
    int b = blockIdx.x, ch = blockIdx.y;
    int tid = threadIdx.x;
    __shared__ float attnS[16], tkS[16];
    __shared__ float bins[128 * 9];
    float* my = bins + tid * 9;
#pragma unroll
    for (int j = 0; j < 8; ++j) my[j] = 0.f;
    if (tid < 16) { attnS[tid] = attn[(size_t)b * UU + ch * 16 + tid]; tkS[tid] = tk[ch * 16 + tid]; }
    __syncthreads();
    const float* ib = inp + ((size_t)b * SS + ch * 16) * FF + tid;
    float accS = 0.f;
#pragma unroll
    for (int s = 0; s < 16; ++s) {
        float w = tkS[s] * ib[(size_t)s * FF];
        float a = attnS[s];
        float t = (w + 2.2f) * 2.5f;
        float cf = floorf(fminf(fmaxf(t, -2.f), 13.f));
        int c = (int)cf;
        float u = t - cf;
        float u2 = u * u, u3 = u2 * u;
        float p[4];
        p[0] = u3 * (1.f / 6.f);
        p[1] = (-3.f * u3 + 3.f * u2 + 3.f * u + 1.f) * (1.f / 6.f);
        p[2] = (3.f * u3 - 6.f * u2 + 4.f) * (1.f / 6.f);
        float onemu = 1.f - u;
        p[3] = onemu * onemu * onemu * (1.f / 6.f);
#pragma unroll
        for (int j = 0; j < 4; ++j) {
            int k2 = c - j;
            if (k2 >= 0 && k2 < 8) atomicAdd(&my[k2], a * p[j]);
        }
        accS += a * (w * sigmoidf(w));
    }
    float* op = Apart + ((size_t)ch * BB + b) * KK;
    float4 v0 = { my[0], my[1], my[2], my[3] };
    float4 v1 = { my[4], my[5], my[6], my[7] };
    *(float4*)(op + tid * 8) = v0;
    *(float4*)(op + tid * 8 + 4) = v1;
    op[1024 + tid] = accS;
}

// ---------------------------------------------------------------------------
// K8: reduce 32 chunks, /S, -> bf16 Aredb[64][1152]
// ---------------------------------------------------------------------------
__global__ void k_ared_red(const float* __restrict__ Apart, unsigned short* __restrict__ Aredb) {
    int idx = blockIdx.x * 256 + threadIdx.x;
    if (idx >= BB * KK) return;
    int b = idx / KK, c = idx % KK;
    float s = 0.f;
#pragma unroll
    for (int ch = 0; ch < NCH; ++ch) s += Apart[((size_t)ch * BB + b) * KK + c];
    Aredb[idx] = f2bf(s * (1.0f / SS));
}

// ---------------------------------------------------------------------------
// K9: direct current = Aredb @ Wt^T -> bf16 into comb_b left half
// ---------------------------------------------------------------------------
__global__ __launch_bounds__(64) void k_cur_direct(const unsigned short* __restrict__ Aredb,
                                                   const unsigned short* __restrict__ Wt,
                                                   unsigned short* __restrict__ comb_b) {
    int lane = threadIdx.x;
    int mt = blockIdx.x, nt = blockIdx.y;
    const unsigned short* pa = Aredb + (size_t)(mt * 16 + (lane & 15)) * KK + (lane >> 4) * 8;
    const unsigned short* pb = Wt + (size_t)(nt * 16 + (lane & 15)) * KK + (lane >> 4) * 8;
    f32x4 acc0 = (f32x4)(0.f), acc1 = (f32x4)(0.f);
#pragma unroll 6
    for (int t = 0; t < KK / 32; t += 2) {
        bf16x8 a0 = *(const bf16x8*)(pa + t * 32);
        bf16x8 b0 = *(const bf16x8*)(pb + t * 32);
        bf16x8 a1 = *(const bf16x8*)(pa + t * 32 + 32);
        bf16x8 b1v = *(const bf16x8*)(pb + t * 32 + 32);
        acc0 = __builtin_amdgcn_mfma_f32_16x16x32_bf16(a0, b0, acc0, 0, 0, 0);
        acc1 = __builtin_amdgcn_mfma_f32_16x16x32_bf16(a1, b1v, acc1, 0, 0, 0);
    }
    int col = lane & 15, quad = lane >> 4;
    int j = nt * 16 + col;
#pragma unroll
    for (int reg = 0; reg < 4; ++reg) {
        int row = mt * 16 + quad * 4 + reg;
        comb_b[(size_t)row * 1024 + j] = f2bf(acc0[reg] + acc1[reg]);
    }
}

// ---------------------------------------------------------------------------
// K10: fused gates + LSTM cell (unchanged from R7)
// ---------------------------------------------------------------------------
__global__ __launch_bounds__(64) void k_lstm_direct(const unsigned short* __restrict__ comb_b,
                                                    const unsigned short* __restrict__ Wgt,
                                                    const float* __restrict__ bf_,
                                                    const float* __restrict__ bi_,
                                                    const float* __restrict__ bc_,
                                                    const float* __restrict__ bo_,
                                                    const float* __restrict__ c_prev,
                                                    float* __restrict__ out) {
    int lane = threadIdx.x;
    int mt = blockIdx.x, ut = blockIdx.y;
    const unsigned short* pa = comb_b + (size_t)(mt * 16 + (lane & 15)) * 1024 + (lane >> 4) * 8;
    size_t brow = (size_t)(ut * 16 + (lane & 15)) * 1024 + (lane >> 4) * 8;
    const unsigned short* pbF = Wgt + brow;
    const unsigned short* pbI = Wgt + (size_t)512 * 1024 + brow;
    const unsigned short* pbC = Wgt + (size_t)1024 * 1024 + brow;
    const unsigned short* pbO = Wgt + (size_t)1536 * 1024 + brow;
    f32x4 aF = (f32x4)(0.f), aI = (f32x4)(0.f), aC = (f32x4)(0.f), aO = (f32x4)(0.f);
#pragma unroll 8
    for (int t = 0; t < 32; ++t) {
        bf16x8 a = *(const bf16x8*)(pa + t * 32);
        aF = __builtin_amdgcn_mfma_f32_16x16x32_bf16(a, *(const bf16x8*)(pbF + t * 32), aF, 0, 0, 0);
        aI = __builtin_amdgcn_mfma_f32_16x16x32_bf16(a, *(const bf16x8*)(pbI + t * 32), aI, 0, 0, 0);
        aC = __builtin_amdgcn_mfma_f32_16x16x32_bf16(a, *(const bf16x8*)(pbC + t * 32), aC, 0, 0, 0);
        aO = __builtin_amdgcn_mfma_f32_16x16x32_bf16(a, *(const bf16x8*)(pbO + t * 32), aO, 0, 0, 0);
    }
    int col = lane & 15, quad = lane >> 4;
    int j = ut * 16 + col;
    float bF = bf_[j], bI = bi_[j], bC = bc_[j], bO = bo_[j];
#pragma unroll
    for (int reg = 0; reg < 4; ++reg) {
        int row = mt * 16 + quad * 4 + reg;
        size_t o = (size_t)row * UU + j;
        float f = sigmoidf(aF[reg] + bF);
        float ii = sigmoidf(aI[reg] + bI);
        float cd = tanhf(aC[reg] + bC);
        float oo = sigmoidf(aO[reg] + bO);
        float cn = f * c_prev[o] + ii * cd;
        out[o] = oo * tanhf(cn);
        out[(size_t)BB * UU + o] = cn;
    }
}

// ---------------------------------------------------------------------------
extern "C" void kernel_launch(void* const* d_in, const int* in_sizes, int n_in,
                              void* d_out, int out_size, void* d_ws, size_t ws_size,
                              hipStream_t stream) {
    const float* inp   = (const float*)d_in[0];
    const float* hprev = (const float*)d_in[1];
    const float* cprev = (const float*)d_in[2];
    const float* tk    = (const float*)d_in[3];
    const float* basew = (const float*)d_in[4];
    const float* splw  = (const float*)d_in[5];
    const float* gw1   = (const float*)d_in[6];
    const float* gb1   = (const float*)d_in[7];
    const float* gw2   = (const float*)d_in[8];
    const float* gb2   = (const float*)d_in[9];
    const float* gw3   = (const float*)d_in[10];
    const float* gb3   = (const float*)d_in[11];
    const float* gw4   = (const float*)d_in[12];
    const float* gb4   = (const float*)d_in[13];
    const float* gsw   = (const float*)d_in[14];
    const float* gsb   = (const float*)d_in[15];
    const float* lng   = (const float*)d_in[16];
    const float* lnb   = (const float*)d_in[17];
    const float* wf    = (const float*)d_in[18];
    const float* bf_   = (const float*)d_in[19];
    const float* wi    = (const float*)d_in[20];
    const float* bi_   = (const float*)d_in[21];
    const float* wc    = (const float*)d_in[22];
    const float* bc_   = (const float*)d_in[23];
    const float* wo    = (const float*)d_in[24];
    const float* bo_   = (const float*)d_in[25];
    float* out = (float*)d_out;

    float* ws = (float*)d_ws;
    size_t o = 0;
    unsigned short* W1t = (unsigned short*)(ws + o); o += (size_t)UU * K3 / 2;
    unsigned short* Wst = (unsigned short*)(ws + o); o += (size_t)UU * K3 / 2;
    unsigned short* Wt  = (unsigned short*)(ws + o); o += (size_t)UU * KK / 2;
    unsigned short* aT = (unsigned short*)(ws + o); o += (size_t)BB * FF * SS / 2;
    unsigned short* dT = (unsigned short*)(ws + o); o += (size_t)BB * FF * SS / 2;
    unsigned short* sigb = (unsigned short*)(ws + o); o += (size_t)BB * K3 / 2;
    float* skippre  = ws + o; o += (size_t)BB * UU;
    unsigned short* h1b = (unsigned short*)(ws + o); o += (size_t)BB * UU / 2;
    unsigned short* h2b = (unsigned short*)(ws + o); o += (size_t)BB * UU / 2;
    float* yv       = ws + o; o += (size_t)BB * UU;
    float* attn     = ws + o; o += (size_t)BB * UU;
    float* Apart    = ws + o; o += (size_t)NCH * BB * KK;            // 9.4 MB
    unsigned short* Aredb = (unsigned short*)(ws + o); o += (size_t)BB * KK / 2;
    unsigned short* W2t = (unsigned short*)(ws + o); o += (size_t)512 * 512 / 2;
    unsigned short* W3t = (unsigned short*)(ws + o); o += (size_t)512 * 512 / 2;
    unsigned short* W4t = (unsigned short*)(ws + o); o += (size_t)512 * 512 / 2;
    unsigned short* Wgt = (unsigned short*)(ws + o); o += (size_t)2048 * 1024 / 2;
    unsigned short* comb_b = (unsigned short*)(ws + o); o += (size_t)BB * 1024 / 2;
    (void)ws_size; (void)in_sizes; (void)n_in; (void)out_size;

    k_prep<<<NB_PREP, 256, 0, stream>>>(inp, tk, splw, basew, hprev, gw1, gsw, gw2, gw3, gw4,
                                        wf, wi, wc, wo, aT, dT, Wt, comb_b,
                                        W1t, Wst, W2t, W3t, W4t, Wgt);
    k_sig_fused<<<BB, 256, 0, stream>>>(aT, dT, inp, tk, sigb);
    k_sig_direct<<<dim3(4, 32, 2), 256, 0, stream>>>(sigb, W1t, Wst, gb1, h1b, skippre);
    k_h2_direct<<<dim3(4, 32), 64, 0, stream>>>(h1b, W2t, gb2, h2b);
    k_glu_direct<<<dim3(4, 32), 64, 0, stream>>>(h2b, W3t, W4t, gb3, gb4, skippre, gsb, yv);
    k_lnsm<<<BB, UU, 0, stream>>>(yv, lng, lnb, attn);
    k_attn_red<<<dim3(BB, NCH), 128, 0, stream>>>(inp, tk, attn, Apart);
    k_ared_red<<<(BB * KK + 255) / 256, 256, 0, stream>>>(Apart, Aredb);
    k_cur_direct<<<dim3(4, 32), 64, 0, stream>>>(Aredb, Wt, comb_b);
    k_lstm_direct<<<dim3(4, 32), 64, 0, stream>>>(comb_b, Wgt, bf_, bi_, bc_, bo_, cprev, out);
}